// Round 2
// baseline (273.827 us; speedup 1.0000x reference)
//
#include <hip/hip_runtime.h>
#include <hip/hip_bf16.h>

typedef float v4f __attribute__((ext_vector_type(4)));
typedef short v8s __attribute__((ext_vector_type(8)));

// ---- workspace layout ----
// float indices:
#define WS_STAT2   0        // 64   conv2 per-ic mean-of-max
#define WS_STATL   64       // 1024 linear per-feature sum
#define WS_B1      1088     // 64
#define WS_B2      1152     // 64
#define WS_WL      1216     // 10240
#define WS_BL      11456    // 10
#define WS_IMAX    11520    // 2048 per-image max|x|
// byte offsets:
#define WS_W1F_B   54272    // 4096 bf16 conv1 weight frags [ot][q][m16][j]
#define WS_WP2_B   62464    // 25*64*64 bf16 conv2 weights [uv][oc][ic]
#define WS_P1_B    267264   // 2048*144*64 bf16 pooled1 NHWC
#define WS_P2_B    38016000 // 2048*1024 fp32 pooled2
// total ~46.4 MB

// per-image max|x| (one wave per image); first blocks also zero the stat accumulators
__global__ void k_stat1(const float* __restrict__ x, float* ws) {
    int n = blockIdx.x, lane = threadIdx.x;
    int zi = n * 64 + lane;
    if (zi < 1088) ws[zi] = 0.f;  // WS_STAT2 + WS_STATL
    const float* p = x + n * 784;
    float m = 0.f;
    for (int i = lane; i < 784; i += 64) m = fmaxf(m, fabsf(p[i]));
#pragma unroll
    for (int off = 32; off; off >>= 1) m = fmaxf(m, __shfl_xor(m, off, 64));
    if (lane == 0) ws[WS_IMAX + n] = m;
}

// conv1 SCINOL weights -> bf16 B-fragments [ot][q][m16][j] (taps>=25 zeroed), bias fp32
__global__ void k_prepw1(const float* __restrict__ w0, const float* __restrict__ S2,
                         const float* __restrict__ G, const float* __restrict__ eta,
                         const float* __restrict__ wM,
                         const float* __restrict__ b0, const float* __restrict__ bS2,
                         const float* __restrict__ bG, const float* __restrict__ beta,
                         float* ws) {
    __shared__ float red[256];
    int tid = threadIdx.x;
    float p = 0.f;
    for (int i = tid; i < 2048; i += 256) p += ws[WS_IMAX + i];
    red[tid] = p;
    __syncthreads();
    for (int s = 128; s > 0; s >>= 1) {
        if (tid < s) red[tid] += red[tid + s];
        __syncthreads();
    }
    float M = fmaxf(red[0] * (1.f / 2048.f), wM[0]);

    int i = blockIdx.x * 256 + tid;
    if (i < 4096) {
        int j = i & 7, m16 = (i >> 3) & 15, q = (i >> 7) & 3, ot = i >> 9;
        int tap = q * 8 + j, oc = ot * 16 + m16;
        float v = 0.f;
        if (tap < 25) {
            int s = oc * 25 + tap;
            float g = G[s];
            float den = sqrtf(S2[s] + M * M);
            float inv = 1.f / den;
            float th = fminf(fmaxf(g * inv, -1.f), 1.f);
            v = w0[s] + ((g != 0.f) ? th * 0.5f * inv * eta[s] : 0.f);
        }
        ((__hip_bfloat16*)((char*)ws + WS_W1F_B))[i] = __float2bfloat16(v);
    } else if (i < 4160) {
        int c = i - 4096;
        float g = bG[c];
        float den = sqrtf(bS2[c] + 1.f);
        float inv = 1.f / den;
        float th = fminf(fmaxf(g * inv, -1.f), 1.f);
        ws[WS_B1 + c] = b0[c] + ((g != 0.f) ? th * 0.5f * inv * beta[c] : 0.f);
    }
}

// conv1 via MFMA implicit GEMM. Block = 256 thr (4 waves) = 1 image.
// Pixels indexed in pooled-window order: P = window*4 + corner, so each lane's
// v4f acc = the 4 corners of one 2x2 pool window -> in-register maxpool.
// M-tile = 16 pixels (4 windows), wave does 9 m-tiles; N = 64 oc = 4 n-tiles; K = 25->32.
__global__ void __launch_bounds__(256, 6)
k_conv1(const float* __restrict__ x, float* ws, __hip_bfloat16* __restrict__ pool1) {
    __shared__ __align__(16) float sX[1024];   // 28x28 image + zero pad
    __shared__ int sMax[64];
    int n = blockIdx.x, tid = threadIdx.x;
    int wv = tid >> 6, lane = tid & 63;
    int m16 = lane & 15, quad = lane >> 4;

    {   // stage image (784 floats) + zero pad to 1024
        const float4* src = (const float4*)(x + (size_t)n * 784);
        float4 v = {0.f, 0.f, 0.f, 0.f};
        if (tid < 196) v = src[tid];
        ((float4*)sX)[tid] = v;
    }
    if (tid < 64) sMax[tid] = 0;

    // B-fragments (weights) + bias, prepped layout in ws
    const ushort* wfrag = (const ushort*)((const char*)ws + WS_W1F_B);
    v8s bfr[4];
    float bias[4];
#pragma unroll
    for (int ot = 0; ot < 4; ++ot) {
        bfr[ot] = *(const v8s*)(wfrag + ((ot * 4 + quad) * 16 + m16) * 8);
        bias[ot] = ws[WS_B1 + ot * 16 + m16];
    }

    // tap offsets for this quad: taps q*8..q*8+7, delta = tap + 23*u (u = tap/5)
    int dj[8];
#pragma unroll
    for (int j = 0; j < 8; ++j) {
        int tap = quad * 8 + j;
        int u = (tap * 13) >> 6;
        dj[j] = tap + 23 * u;
    }

    // A-side pixel coords: P = MT*16 + m16 -> window = MT*4 + (m16>>2), corner = m16&3
    int W0 = wv * 36 + (m16 >> 2);
    int wy = (W0 * 171) >> 11;
    int wx = W0 - wy * 12;
    int coff = 28 * ((m16 >> 1) & 1) + (m16 & 1);

    __syncthreads();

    float vmax[4] = {0.f, 0.f, 0.f, 0.f};
    __hip_bfloat16* op = pool1 + (size_t)n * 9216;
    for (int mt = 0; mt < 9; ++mt) {
        int base = 56 * wy + 2 * wx + coff;
        union { v8s v; ushort us[8]; } ua;
#pragma unroll
        for (int j = 0; j < 8; ++j)
            ua.us[j] = __bfloat16_as_ushort(__float2bfloat16(sX[base + dj[j]]));

        v4f z = {0.f, 0.f, 0.f, 0.f};
        v4f acc[4];
#pragma unroll
        for (int ot = 0; ot < 4; ++ot)
            acc[ot] = __builtin_amdgcn_mfma_f32_16x16x32_bf16(ua.v, bfr[ot], z, 0, 0, 0);

        int Wd = (wv * 9 + mt) * 4 + quad;  // window this lane's acc belongs to
#pragma unroll
        for (int ot = 0; ot < 4; ++ot) {
            v4f a = acc[ot];
            float m = fmaxf(fmaxf(a[0], a[1]), fmaxf(a[2], a[3]));
            float pv = fmaxf(m + bias[ot], 0.f);
            vmax[ot] = fmaxf(vmax[ot], pv);
            op[Wd * 64 + ot * 16 + m16] = __float2bfloat16(pv);
        }
        // advance window coords by 4
        wx += 4;
        if (wx >= 12) { wx -= 12; ++wy; }
    }

    // per-channel max stat -> mean over batch
#pragma unroll
    for (int ot = 0; ot < 4; ++ot) {
        float m = vmax[ot];
        m = fmaxf(m, __shfl_xor(m, 16, 64));
        m = fmaxf(m, __shfl_xor(m, 32, 64));
        if (lane < 16) atomicMax(&sMax[ot * 16 + lane], __float_as_int(m));
    }
    __syncthreads();
    if (tid < 64) atomicAdd(&ws[WS_STAT2 + tid], __int_as_float(sMax[tid]) * (1.f / 2048.f));
}

// conv2 SCINOL weights -> bf16 [uv][oc][ic]; bias -> ws[WS_B2]
__global__ void k_prepw2(const float* __restrict__ w0, const float* __restrict__ S2,
                         const float* __restrict__ G, const float* __restrict__ eta,
                         const float* __restrict__ wM,
                         const float* __restrict__ b0, const float* __restrict__ bS2,
                         const float* __restrict__ bG, const float* __restrict__ beta,
                         float* ws, __hip_bfloat16* __restrict__ wp2) {
    int i = blockIdx.x * 256 + threadIdx.x;  // exactly 102400
    int uv = i >> 12, rem = i & 4095, oc = rem >> 6, ic = rem & 63;
    int s = oc * 1600 + ic * 25 + uv;
    float M = fmaxf(ws[WS_STAT2 + ic], wM[ic]);
    float g = G[s];
    float den = sqrtf(S2[s] + M * M);
    float inv = 1.f / den;
    float th = fminf(fmaxf(g * inv, -1.f), 1.f);
    float v = w0[s] + ((g != 0.f) ? th * 0.5f * inv * eta[s] : 0.f);
    wp2[i] = __float2bfloat16(v);
    if (blockIdx.x == 0 && threadIdx.x < 64) {
        int c = threadIdx.x;
        float gb = bG[c];
        float den2 = sqrtf(bS2[c] + 1.f);
        float inv2 = 1.f / den2;
        float th2 = fminf(fmaxf(gb * inv2, -1.f), 1.f);
        ws[WS_B2 + c] = b0[c] + ((gb != 0.f) ? th2 * 0.5f * inv2 * beta[c] : 0.f);
    }
}

// conv2 implicit GEMM: block = 128 thr (2 waves), 2 images; wave = 1 image,
// 4x4 tiles of mfma_f32_16x16x32_bf16 (M=64 px, N=64 oc), K-loop over 25 taps x 64 ic.
__global__ void __launch_bounds__(128, 2)
k_conv2(const ushort* __restrict__ pool1, const ushort* __restrict__ wp2,
        const float* __restrict__ ws, float* __restrict__ pool2) {
    __shared__ __align__(16) ushort sImg[2 * 9216];  // 2 images NHWC bf16
    __shared__ __align__(16) ushort sW[4096];        // one tap: [oc][ic]
    int tid = threadIdx.x;
    int wv = tid >> 6, lane = tid & 63;
    int n0 = blockIdx.x * 2;

    {   // stage both images (contiguous 36864 B)
        const uint4* src = (const uint4*)(pool1 + (size_t)n0 * 9216);
        uint4* dst = (uint4*)sImg;
#pragma unroll
        for (int i = 0; i < 18; ++i) dst[tid + i * 128] = src[tid + i * 128];
    }

    int m16 = lane & 15, quad = lane >> 4;
    int q8 = quad * 8;
    int x0 = m16 & 7;
    int yb = m16 >> 3;
    v4f acc[4][4];
#pragma unroll
    for (int i = 0; i < 4; ++i)
#pragma unroll
        for (int j = 0; j < 4; ++j) acc[i][j] = (v4f){0.f, 0.f, 0.f, 0.f};

    const ushort* simg = sImg + wv * 9216;
    int uvIdx = 0;
    for (int u = 0; u < 5; ++u)
        for (int v = 0; v < 5; ++v) {
            __syncthreads();  // prev compute done before overwriting sW
            {
                const uint4* wsrc = (const uint4*)(wp2 + uvIdx * 4096);
                uint4* wdst = (uint4*)sW;
#pragma unroll
                for (int i = 0; i < 4; ++i) wdst[tid + i * 128] = wsrc[tid + i * 128];
            }
            __syncthreads();
            int rb[4];
#pragma unroll
            for (int pt = 0; pt < 4; ++pt)
                rb[pt] = ((pt * 2 + yb + u) * 12 + x0 + v) * 64 + q8;
#pragma unroll
            for (int kc = 0; kc < 2; ++kc) {
                v8s a[4], bf[4];
#pragma unroll
                for (int pt = 0; pt < 4; ++pt)
                    a[pt] = *(const v8s*)(simg + rb[pt] + kc * 32);
#pragma unroll
                for (int ot = 0; ot < 4; ++ot)
                    bf[ot] = *(const v8s*)(sW + (ot * 16 + m16) * 64 + kc * 32 + q8);
#pragma unroll
                for (int pt = 0; pt < 4; ++pt)
#pragma unroll
                    for (int ot = 0; ot < 4; ++ot)
                        acc[pt][ot] = __builtin_amdgcn_mfma_f32_16x16x32_bf16(
                            a[pt], bf[ot], acc[pt][ot], 0, 0, 0);
            }
            ++uvIdx;
        }

    // epilogue: bias + relu + 2x2 maxpool -> pooled2[n][oc*16+py*4+px] fp32
    int n = n0 + wv;
    float bv[4];
#pragma unroll
    for (int ot = 0; ot < 4; ++ot) bv[ot] = ws[WS_B2 + ot * 16 + m16];
    float* outp = pool2 + (size_t)n * 1024;
#pragma unroll
    for (int pt = 0; pt < 4; ++pt)
#pragma unroll
        for (int ot = 0; ot < 4; ++ot) {
            v4f a = acc[pt][ot];
            float m01 = fmaxf(a[0], a[1]);
            float m23 = fmaxf(a[2], a[3]);
            m01 = fmaxf(m01, __shfl_xor(m01, 32, 64));
            m23 = fmaxf(m23, __shfl_xor(m23, 32, 64));
            if (lane < 32) {
                int oc = ot * 16 + m16;
                int f = oc * 16 + pt * 4 + (quad & 1) * 2;
                outp[f] = fmaxf(m01 + bv[ot], 0.f);
                outp[f + 1] = fmaxf(m23 + bv[ot], 0.f);
            }
        }
}

// per-feature sum over batch (h >= 0 so |h| = h); 256 blocks x 8 images
__global__ void k_statl(const float* __restrict__ pool2, float* ws) {
    int b = blockIdx.x, tid = threadIdx.x;
    float4 s = {0.f, 0.f, 0.f, 0.f};
    for (int im = 0; im < 8; ++im) {
        float4 v = ((const float4*)(pool2 + (size_t)(b * 8 + im) * 1024))[tid];
        s.x += v.x; s.y += v.y; s.z += v.z; s.w += v.w;
    }
    atomicAdd(&ws[WS_STATL + tid * 4 + 0], s.x);
    atomicAdd(&ws[WS_STATL + tid * 4 + 1], s.y);
    atomicAdd(&ws[WS_STATL + tid * 4 + 2], s.z);
    atomicAdd(&ws[WS_STATL + tid * 4 + 3], s.w);
}

__global__ void k_prepwl(const float* __restrict__ w0, const float* __restrict__ S2,
                         const float* __restrict__ G, const float* __restrict__ eta,
                         const float* __restrict__ wM,
                         const float* __restrict__ b0, const float* __restrict__ bS2,
                         const float* __restrict__ bG, const float* __restrict__ beta,
                         float* ws) {
    int i = blockIdx.x * 256 + threadIdx.x;
    if (i < 10240) {
        int f = i & 1023;
        float stat = ws[WS_STATL + f] * (1.f / 2048.f);
        float M = fmaxf(wM[i], stat);
        float s2 = S2[i];
        float den = sqrtf(s2 + M * M);
        float inv = 1.f / den;
        float th = fminf(fmaxf(G[i] * inv, -1.f), 1.f);
        ws[WS_WL + i] = w0[i] + ((s2 != 0.f) ? th * 0.5f * inv * eta[i] : 0.f);  // cond = wS2 != 0
    } else if (i < 10250) {
        int c = i - 10240;
        float s2 = bS2[c];
        float den = sqrtf(s2 + 1.f);
        float inv = 1.f / den;
        float th = fminf(fmaxf(bG[c] * inv, -1.f), 1.f);
        ws[WS_BL + c] = b0[c] + ((s2 != 0.f) ? th * 0.5f * inv * beta[c] : 0.f);  // cond = bS2 != 0
    }
}

// (2048,1024) x (1024,10)^T + b: wave per image, lane-strided features
__global__ void k_linear(const float* __restrict__ pool2, const float* __restrict__ ws,
                         float* __restrict__ out) {
    int tid = threadIdx.x;
    int wv = tid >> 6, lane = tid & 63;
    int n = blockIdx.x * 4 + wv;
    const float* hp = pool2 + (size_t)n * 1024;
    float h[16];
#pragma unroll
    for (int j = 0; j < 16; ++j) h[j] = hp[j * 64 + lane];
    for (int oc = 0; oc < 10; ++oc) {
        const float* wp = ws + WS_WL + oc * 1024;
        float d = 0.f;
#pragma unroll
        for (int j = 0; j < 16; ++j) d = fmaf(h[j], wp[j * 64 + lane], d);
#pragma unroll
        for (int off = 32; off; off >>= 1) d += __shfl_xor(d, off, 64);
        if (lane == 0) out[n * 10 + oc] = d + ws[WS_BL + oc];
    }
}

extern "C" void kernel_launch(void* const* d_in, const int* in_sizes, int n_in,
                              void* d_out, int out_size, void* d_ws, size_t ws_size,
                              hipStream_t stream) {
    const float* x = (const float*)d_in[0];
    float* ws = (float*)d_ws;
    __hip_bfloat16* wp2 = (__hip_bfloat16*)((char*)d_ws + WS_WP2_B);
    __hip_bfloat16* p1 = (__hip_bfloat16*)((char*)d_ws + WS_P1_B);
    float* p2 = (float*)((char*)d_ws + WS_P2_B);
    float* out = (float*)d_out;

    k_stat1<<<2048, 64, 0, stream>>>(x, ws);
    k_prepw1<<<17, 256, 0, stream>>>(
        (const float*)d_in[1], (const float*)d_in[2], (const float*)d_in[3],
        (const float*)d_in[4], (const float*)d_in[5], (const float*)d_in[6],
        (const float*)d_in[7], (const float*)d_in[8], (const float*)d_in[9], ws);
    k_conv1<<<2048, 256, 0, stream>>>(x, ws, p1);
    k_prepw2<<<400, 256, 0, stream>>>(
        (const float*)d_in[10], (const float*)d_in[11], (const float*)d_in[12],
        (const float*)d_in[13], (const float*)d_in[14], (const float*)d_in[15],
        (const float*)d_in[16], (const float*)d_in[17], (const float*)d_in[18], ws, wp2);
    k_conv2<<<1024, 128, 0, stream>>>((const ushort*)p1, (const ushort*)wp2, ws, p2);
    k_statl<<<256, 256, 0, stream>>>(p2, ws);
    k_prepwl<<<41, 256, 0, stream>>>(
        (const float*)d_in[19], (const float*)d_in[20], (const float*)d_in[21],
        (const float*)d_in[22], (const float*)d_in[23], (const float*)d_in[24],
        (const float*)d_in[25], (const float*)d_in[26], (const float*)d_in[27], ws);
    k_linear<<<512, 256, 0, stream>>>(p2, ws, out);
}